// Round 1
// baseline (430.934 us; speedup 1.0000x reference)
//
#include <hip/hip_runtime.h>
#include <hip/hip_bf16.h>
#include <stdint.h>

// LcRnnCell, DEPTH=1 specialization.
// B=4096, E=512, H=512. pd in {0,1}.
// pd==0: out_a=[0;na10], out_b=[0;nb10], depth=1,f=1,j=0  (no softmax needed)
//   na10 = [X,b_dm1]@Wa10^T ; nb10 = [X,na10]@Wb10^T
// pd==1: nb11 = [X,b_d]@Wb11^T ; z_c = Watt[c]·[0,a_d,b_d,0,a_d,nb11]
//   sel over {0,1,3}; col0: na00=[X,b_dm1,a_d]@Wa00^T, nb00=[X,a_d,na00]@Wb00^T
//   col1: zeros; col3: [a_d; nb11]. Ties additive (reference sign() semantics).

enum GMode { M_A10 = 0, M_B10 = 1, M_B11 = 2, M_A00 = 3, M_B00 = 4 };

struct GPtrs {
  const float* X;
  const float* pa;
  const float* pb;
  const float* W;
  const float* na00ws;
  float* nb11ws;
  float* nextA;
  float* nextB;
  const int* list;
  const int* cnt;
};

__global__ void kz(float4* outab, float4* wsab, int* cnt, long n1f, long n2f) {
  long i = (long)blockIdx.x * blockDim.x + threadIdx.x;
  float4 z = make_float4(0.f, 0.f, 0.f, 0.f);
  if (i * 4 < n1f) outab[i] = z;
  if (i * 4 < n2f) wsab[i] = z;
  if (i < 4) cnt[i] = 0;
}

__global__ void kclassify(const int* __restrict__ pdep, float* dep_out, float* f_out,
                          float* j_out, int* cnt, int* list0, int* list1, int Bn) {
  int r = blockIdx.x * blockDim.x + threadIdx.x;
  if (r >= Bn) return;
  int d = pdep[r];
  if (d == 0) {
    int p = atomicAdd(&cnt[0], 1);
    list0[p] = r;
    dep_out[r] = 1.0f;  // sel forced to col2: depth = pd+1 = 1
    f_out[r] = 1.0f;
    j_out[r] = 0.0f;
  } else {
    int p = atomicAdd(&cnt[1], 1);
    list1[p] = r;
  }
}

// Tiled fp32 GEMM: C[m,n] = sum_k A[m,k]*W[n,k], gathered A rows, K-split with
// atomicAdd epilogue into zeroed destinations. BM=BN=64, BK=32, 256 thr, 4x4 micro.
template <int MODE, int KTOT, int SPLIT>
__global__ __launch_bounds__(256) void gemm_k(GPtrs P) {
  const int KB = KTOT / SPLIT;
  const int KSTEPS = KB / 32;
  int bid = blockIdx.x;
  int ks = bid % SPLIT;
  int nt = (bid / SPLIT) & 7;        // 512/64 = 8 col tiles
  int mt = bid / (SPLIT * 8);
  int cnt = *P.cnt;
  if (mt * 64 >= cnt) return;

  __shared__ float As[32][68];
  __shared__ float Bs[32][68];

  const int tid = threadIdx.x;
  const int lrow = tid >> 2;         // 0..63
  const int lc8 = (tid & 3) * 8;     // 0,8,16,24
  const int tn = tid & 15, tm = tid >> 4;

  int mg_a = mt * 64 + lrow;
  int r_a = (mg_a < cnt) ? P.list[mg_a] : -1;

  const float* s0 = nullptr;
  const float* s1 = nullptr;
  const float* s2 = nullptr;
  if (r_a >= 0) {
    s0 = P.X + (long)r_a * 512;
    if (MODE == M_A10) {
      s1 = P.pb + (long)r_a * 1024;                 // b_dm1
    } else if (MODE == M_B10) {
      s1 = P.nextA + (long)r_a * 1024 + 512;        // na10 (written by K1)
    } else if (MODE == M_B11) {
      s1 = P.pb + (long)r_a * 1024 + 512;           // b_d
    } else if (MODE == M_A00) {
      s1 = P.pb + (long)r_a * 1024;                 // b_dm1
      s2 = P.pa + (long)r_a * 1024 + 512;           // a_d
    } else {                                        // M_B00
      s1 = P.pa + (long)r_a * 1024 + 512;           // a_d
      s2 = P.na00ws + (long)mg_a * 512;             // na00 (compacted idx)
    }
  }

  const int nrow = nt * 64 + lrow;
  const float* bsrc = P.W + (long)nrow * KTOT;

  float acc[4][4];
#pragma unroll
  for (int i = 0; i < 4; ++i)
#pragma unroll
    for (int j = 0; j < 4; ++j) acc[i][j] = 0.f;

  for (int kt = 0; kt < KSTEPS; ++kt) {
    int k0 = ks * KB + kt * 32;
    float4 av0 = make_float4(0.f, 0.f, 0.f, 0.f), av1 = av0;
    if (r_a >= 0) {
      int seg = k0 >> 9;
      int kin = (k0 & 511) + lc8;
      const float* ab = (seg == 0) ? s0 : ((seg == 1) ? s1 : s2);
      av0 = *(const float4*)(ab + kin);
      av1 = *(const float4*)(ab + kin + 4);
    }
    float4 bv0 = *(const float4*)(bsrc + k0 + lc8);
    float4 bv1 = *(const float4*)(bsrc + k0 + lc8 + 4);

    __syncthreads();
    As[lc8 + 0][lrow] = av0.x; As[lc8 + 1][lrow] = av0.y;
    As[lc8 + 2][lrow] = av0.z; As[lc8 + 3][lrow] = av0.w;
    As[lc8 + 4][lrow] = av1.x; As[lc8 + 5][lrow] = av1.y;
    As[lc8 + 6][lrow] = av1.z; As[lc8 + 7][lrow] = av1.w;
    Bs[lc8 + 0][lrow] = bv0.x; Bs[lc8 + 1][lrow] = bv0.y;
    Bs[lc8 + 2][lrow] = bv0.z; Bs[lc8 + 3][lrow] = bv0.w;
    Bs[lc8 + 4][lrow] = bv1.x; Bs[lc8 + 5][lrow] = bv1.y;
    Bs[lc8 + 6][lrow] = bv1.z; Bs[lc8 + 7][lrow] = bv1.w;
    __syncthreads();

#pragma unroll
    for (int kk = 0; kk < 32; ++kk) {
      float4 a4 = *(const float4*)&As[kk][tm * 4];
      float4 b4 = *(const float4*)&Bs[kk][tn * 4];
      float av[4] = {a4.x, a4.y, a4.z, a4.w};
      float bv[4] = {b4.x, b4.y, b4.z, b4.w};
#pragma unroll
      for (int i = 0; i < 4; ++i)
#pragma unroll
        for (int j = 0; j < 4; ++j) acc[i][j] += av[i] * bv[j];
    }
  }

#pragma unroll
  for (int i = 0; i < 4; ++i) {
    int mg = mt * 64 + tm * 4 + i;
    if (mg >= cnt) continue;
    int r = P.list[mg];
#pragma unroll
    for (int j = 0; j < 4; ++j) {
      int col = nt * 64 + tn * 4 + j;
      float v = acc[i][j];
      if (MODE == M_A10) {
        atomicAdd(P.nextA + (long)r * 1024 + 512 + col, v);
      } else if (MODE == M_B10) {
        atomicAdd(P.nextB + (long)r * 1024 + 512 + col, v);
      } else if (MODE == M_B11) {
        atomicAdd(P.nb11ws + (long)mg * 512 + col, v);
      } else if (MODE == M_A00) {
        atomicAdd((float*)P.na00ws + (long)mg * 512 + col, v);
      } else {  // M_B00: nb00 into nextB; once (ks==0) add na00 into nextA
        atomicAdd(P.nextB + (long)r * 1024 + 512 + col, v);
        if (ks == 0)
          atomicAdd(P.nextA + (long)r * 1024 + 512 + col,
                    P.na00ws[(long)mg * 512 + col]);
      }
    }
  }
}

// One 64-lane wave per pd==1 row: z logits, exact softmax+sign selection,
// writes depth/f/j, col3 payload, and pushes sel0 rows to list2.
__global__ __launch_bounds__(64) void kselect(
    const float* __restrict__ pa, const float* __restrict__ pb,
    const float* __restrict__ watt, const float* __restrict__ nb11ws,
    float* nextA, float* nextB, float* dep_out, float* f_out, float* j_out,
    int* cnt, const int* __restrict__ list1, int* list2) {
  int i1 = blockIdx.x;
  if (i1 >= cnt[1]) return;
  int r = list1[i1];
  int lane = threadIdx.x;
  const float* a_d = pa + (long)r * 1024 + 512;
  const float* b_d = pb + (long)r * 1024 + 512;
  const float* nb = nb11ws + (long)i1 * 512;

  float z[4] = {0.f, 0.f, 0.f, 0.f};
  for (int u = 0; u < 8; ++u) {
    int h = u * 64 + lane;
    float la = a_d[h], lb = b_d[h], ln = nb[h];
#pragma unroll
    for (int c = 0; c < 4; ++c) {
      const float* wc = watt + (long)c * 4096;
      z[c] += wc[1024 + h] * la + wc[1536 + h] * lb + wc[3072 + h] * la +
              wc[3584 + h] * ln;
    }
  }
#pragma unroll
  for (int c = 0; c < 4; ++c) {
    float v = z[c];
    for (int off = 32; off; off >>= 1) v += __shfl_xor(v, off);
    z[c] = v;
  }
  float m = fmaxf(fmaxf(z[0], z[1]), fmaxf(z[2], z[3]));
  float e0 = expf(z[0] - m), e1 = expf(z[1] - m), e2 = expf(z[2] - m),
        e3 = expf(z[3] - m);
  float s = e0 + e1 + e2 + e3;
  float att0 = e0 / s, att1 = e1 / s, att3 = e3 / s;  // att2 masked (pd==1)
  float amax = fmaxf(att0, fmaxf(att1, att3));
  float s0 = (att0 >= amax) ? 1.f : 0.f;
  float s1v = (att1 >= amax) ? 1.f : 0.f;
  float s3 = (att3 >= amax) ? 1.f : 0.f;

  if (lane == 0) {
    dep_out[r] = s0 + s3;      // pd==1: sel0*1 + sel1*0 + sel3*1
    f_out[r] = s3;             // sel2+sel3
    j_out[r] = s1v + s3;       // sel1+sel3
    if (s0 > 0.f) {
      int p = atomicAdd(&cnt[2], 1);
      list2[p] = r;
    }
  }
  if (s3 > 0.f) {
    float4* dA = (float4*)(nextA + (long)r * 1024 + 512);
    float4* dB = (float4*)(nextB + (long)r * 1024 + 512);
    const float4* sa = (const float4*)a_d;
    const float4* sb = (const float4*)nb;
    dA[lane * 2] = sa[lane * 2];
    dA[lane * 2 + 1] = sa[lane * 2 + 1];
    dB[lane * 2] = sb[lane * 2];
    dB[lane * 2 + 1] = sb[lane * 2 + 1];
  }
}

extern "C" void kernel_launch(void* const* d_in, const int* in_sizes, int n_in,
                              void* d_out, int out_size, void* d_ws, size_t ws_size,
                              hipStream_t stream) {
  const float* X = (const float*)d_in[0];
  const float* pa = (const float*)d_in[1];
  const float* pb = (const float*)d_in[2];
  const int* pdep = (const int*)d_in[3];
  const float* Wa00 = (const float*)d_in[4];
  const float* Wa10 = (const float*)d_in[5];
  const float* Wb00 = (const float*)d_in[6];
  const float* Wb11 = (const float*)d_in[7];
  const float* Wb10 = (const float*)d_in[8];
  const float* Watt = (const float*)d_in[10];  // d_in[9]=Wb01 unused (nb01==0)

  const int Bn = in_sizes[3];  // prev_depth has B elements
  float* out = (float*)d_out;
  float* nextA = out;
  float* nextB = out + (long)Bn * 1024;
  float* dep = out + (long)2 * Bn * 1024;
  float* fo = dep + Bn;
  float* jo = fo + Bn;

  char* ws = (char*)d_ws;
  int* cnt = (int*)(ws);
  int* list0 = (int*)(ws + 64);
  int* list1 = (int*)(ws + 64 + 4096 * 4);
  int* list2 = (int*)(ws + 64 + 8192 * 4);
  float* nb11ws = (float*)(ws + 65536);
  float* na00ws = (float*)(ws + 65536 + (size_t)4096 * 512 * 4);

  // Zero next_a/next_b (33.5MB), nb11+na00 ws (16MB, contiguous), counters.
  long nab = (long)2 * Bn * 1024;
  long nws = (long)2 * Bn * 512;
  int zblocks = (int)((nab / 4 + 255) / 256);
  kz<<<zblocks, 256, 0, stream>>>((float4*)out, (float4*)nb11ws, cnt, nab, nws);

  kclassify<<<(Bn + 255) / 256, 256, 0, stream>>>(pdep, dep, fo, jo, cnt, list0,
                                                  list1, Bn);

  GPtrs P{};
  P.X = X; P.pa = pa; P.pb = pb;
  P.na00ws = na00ws; P.nb11ws = nb11ws;
  P.nextA = nextA; P.nextB = nextB;

  int mtmax = (Bn + 63) / 64;

  P.W = Wa10; P.list = list0; P.cnt = &cnt[0];
  gemm_k<M_A10, 1024, 2><<<mtmax * 8 * 2, 256, 0, stream>>>(P);
  P.W = Wb10;
  gemm_k<M_B10, 1024, 2><<<mtmax * 8 * 2, 256, 0, stream>>>(P);
  P.W = Wb11; P.list = list1; P.cnt = &cnt[1];
  gemm_k<M_B11, 1024, 2><<<mtmax * 8 * 2, 256, 0, stream>>>(P);

  kselect<<<Bn, 64, 0, stream>>>(pa, pb, Watt, nb11ws, nextA, nextB, dep, fo,
                                 jo, cnt, list1, list2);

  P.W = Wa00; P.list = list2; P.cnt = &cnt[2];
  gemm_k<M_A00, 1536, 4><<<mtmax * 8 * 4, 256, 0, stream>>>(P);
  P.W = Wb00;
  gemm_k<M_B00, 1536, 4><<<mtmax * 8 * 4, 256, 0, stream>>>(P);
}